// Round 1
// baseline (9813.716 us; speedup 1.0000x reference)
//
#include <hip/hip_runtime.h>
#include <hip/hip_bf16.h>

#define B_ 4096
#define D_ 32
#define H_ 1024

// ---------------- layer 0: a1[b,h] = relu(sum_{k<=h%31} x[b,k]*W0[h,k] + b0[h]) ----------------
__global__ void layer0_kernel(const float* __restrict__ x,
                              const float* __restrict__ W0,
                              const float* __restrict__ b0,
                              float* __restrict__ out) {
    int b = blockIdx.y;
    int h = blockIdx.x * blockDim.x + threadIdx.x;
    __shared__ float xs[D_];
    if (threadIdx.x < D_) xs[threadIdx.x] = x[b * D_ + threadIdx.x];
    __syncthreads();
    int kmax = h % 31;             // d_hid[h]; mask m0[h,k] = (h%31 >= k)
    float acc = b0[h];
    const float* wr = W0 + (size_t)h * D_;
    for (int k = 0; k <= kmax; k++) acc = fmaf(xs[k], wr[k], acc);
    out[(size_t)b * H_ + h] = fmaxf(acc, 0.f);
}

// ---------------- hidden layers: C = relu(A @ (mask*W)^T + bias) ----------------
// A: [M=4096, K=1024] row-major.  W: [N=1024, K=1024] row-major.  mask(n,k) = (n%31 >= k%31)
#define BM 64
#define BN 64
#define BK 16
#define PAD 4

__global__ __launch_bounds__(256) void gemm_masked_relu(
        const float* __restrict__ A,
        const float* __restrict__ W,
        const float* __restrict__ bias,
        float* __restrict__ C) {
    const int K = H_, N = H_;
    __shared__ __align__(16) float As[BK][BM + PAD];   // row stride 68 floats = 272B (16B mult)
    __shared__ __align__(16) float Ws[BK][BN + PAD];
    int tid = threadIdx.x;
    int mBase = blockIdx.y * BM;
    int nBase = blockIdx.x * BN;
    int tx = tid & 15, ty = tid >> 4;
    int lr = tid >> 2;            // 0..63: tile row for staging
    int lc = (tid & 3) << 2;      // 0,4,8,12: k-group for staging
    int nmod = (nBase + lr) % 31; // degree of output unit this thread stages
    const float* Aptr = A + (size_t)(mBase + lr) * K + lc;
    const float* Wptr = W + (size_t)(nBase + lr) * K + lc;
    float acc[4][4] = {};

    for (int k0 = 0; k0 < K; k0 += BK) {
        float4 av = *(const float4*)(Aptr + k0);
        float4 wv = *(const float4*)(Wptr + k0);
        float wf[4] = {wv.x, wv.y, wv.z, wv.w};
        #pragma unroll
        for (int j = 0; j < 4; j++) {
            if (nmod < (k0 + lc + j) % 31) wf[j] = 0.f;   // apply autoregressive mask
        }
        __syncthreads();
        As[lc + 0][lr] = av.x;
        As[lc + 1][lr] = av.y;
        As[lc + 2][lr] = av.z;
        As[lc + 3][lr] = av.w;
        Ws[lc + 0][lr] = wf[0];
        Ws[lc + 1][lr] = wf[1];
        Ws[lc + 2][lr] = wf[2];
        Ws[lc + 3][lr] = wf[3];
        __syncthreads();
        #pragma unroll
        for (int kk = 0; kk < BK; kk++) {
            float4 a4 = *(const float4*)(&As[kk][ty << 2]);
            float4 w4 = *(const float4*)(&Ws[kk][tx << 2]);
            float aa[4] = {a4.x, a4.y, a4.z, a4.w};
            float ww[4] = {w4.x, w4.y, w4.z, w4.w};
            #pragma unroll
            for (int i = 0; i < 4; i++)
                #pragma unroll
                for (int j = 0; j < 4; j++)
                    acc[i][j] = fmaf(aa[i], ww[j], acc[i][j]);
        }
    }

    int col0 = nBase + (tx << 2);
    float bb[4] = {bias[col0], bias[col0 + 1], bias[col0 + 2], bias[col0 + 3]};
    #pragma unroll
    for (int i = 0; i < 4; i++) {
        int row = mBase + (ty << 2) + i;
        float4 o;
        o.x = fmaxf(acc[i][0] + bb[0], 0.f);
        o.y = fmaxf(acc[i][1] + bb[1], 0.f);
        o.z = fmaxf(acc[i][2] + bb[2], 0.f);
        o.w = fmaxf(acc[i][3] + bb[3], 0.f);
        *(float4*)(C + (size_t)row * N + col0) = o;
    }
}

// ---------------- output step: mu/log_std for column idx, update x ----------------
// theta[:,idx] uses Wout row idx, theta[:,idx+32] uses row idx+32; both masked by (h%31 <= idx-1)
__global__ void out_step_kernel(const float* __restrict__ a,
                                const float* __restrict__ Wout,
                                const float* __restrict__ bout,
                                const float* __restrict__ z,
                                float* __restrict__ x,
                                int idx) {
    int lane = threadIdx.x & 63;
    int b = blockIdx.x * (blockDim.x >> 6) + (threadIdx.x >> 6);
    const float* ar  = a + (size_t)b * H_;
    const float* wmu = Wout + (size_t)idx * H_;
    const float* wls = Wout + (size_t)(idx + D_) * H_;
    float smu = 0.f, sls = 0.f;
    for (int h = lane; h < H_; h += 64) {
        if ((h % 31) < idx) {       // mask: d_hid[h] <= idx-1
            float av = ar[h];
            smu = fmaf(av, wmu[h], smu);
            sls = fmaf(av, wls[h], sls);
        }
    }
    #pragma unroll
    for (int off = 32; off > 0; off >>= 1) {
        smu += __shfl_down(smu, off);
        sls += __shfl_down(sls, off);
    }
    if (lane == 0) {
        float mu = smu + bout[idx];
        float ls = sls + bout[idx + D_];
        x[(size_t)b * D_ + idx] = fmaf(z[(size_t)b * D_ + idx], expf(ls), mu);
    }
}

extern "C" void kernel_launch(void* const* d_in, const int* in_sizes, int n_in,
                              void* d_out, int out_size, void* d_ws, size_t ws_size,
                              hipStream_t stream) {
    const float* z    = (const float*)d_in[0];
    const float* W0   = (const float*)d_in[1];
    const float* b0   = (const float*)d_in[2];
    const float* Wh   = (const float*)d_in[3];   // [2, H, H]
    const float* bh   = (const float*)d_in[4];   // [2, H]
    const float* Wout = (const float*)d_in[5];   // [64, H]
    const float* bout = (const float*)d_in[6];   // [64]

    float* x  = (float*)d_out;                   // [B, D] — running autoregressive state & final output
    float* a1 = (float*)d_ws;                    // [B, H]
    float* a2 = a1 + (size_t)B_ * H_;            // [B, H]

    // x starts at zero (harness poisons d_out with 0xAA)
    hipMemsetAsync(d_out, 0, (size_t)B_ * D_ * sizeof(float), stream);

    dim3 blk(256);
    dim3 g0(H_ / 256, B_);
    dim3 gg(H_ / BN, B_ / BM);
    dim3 go(B_ / 4);   // 4 waves (4 batch rows) per 256-thread block

    for (int idx = 0; idx < D_; idx++) {
        layer0_kernel<<<g0, blk, 0, stream>>>(x, W0, b0, a1);
        gemm_masked_relu<<<gg, blk, 0, stream>>>(a1, Wh,           bh,      a2);
        gemm_masked_relu<<<gg, blk, 0, stream>>>(a2, Wh + H_ * H_, bh + H_, a1);
        out_step_kernel<<<go, blk, 0, stream>>>(a1, Wout, bout, z, x, idx);
    }
}

// Round 2
// 3301.990 us; speedup vs baseline: 2.9721x; 2.9721x over previous
//
#include <hip/hip_runtime.h>
#include <hip/hip_bf16.h>

#define B_ 4096
#define D_ 32
#define H_ 1024

typedef __attribute__((ext_vector_type(8))) short short8;
typedef __attribute__((ext_vector_type(4))) float floatx4;

__device__ inline unsigned short f2bf(float f) {      // fp32 -> bf16 bits, RNE
    unsigned u = __float_as_uint(f);
    unsigned r = (u + 0x7FFF + ((u >> 16) & 1)) >> 16;
    return (unsigned short)r;
}
__device__ inline float bf2f(unsigned short b) {
    return __uint_as_float(((unsigned)b) << 16);
}

__device__ inline void glds16(const void* g, void* l) {
    __builtin_amdgcn_global_load_lds(
        (const __attribute__((address_space(1))) unsigned int*)g,
        (__attribute__((address_space(3))) unsigned int*)l, 16, 0, 0);
}

// ---- prep: Wh[2,H,H] fp32 -> masked bf16.  mask(n,k) = (n%31 >= k%31) ----
__global__ void convert_wh(const float* __restrict__ Wh, unsigned short* __restrict__ Wb) {
    int i4 = blockIdx.x * 256 + threadIdx.x;       // float4 group over 2*H*H
    int n = (i4 >> 8) & 1023;                      // 256 float4 per K-row
    int k0 = (i4 & 255) * 4;
    const float4 v = ((const float4*)Wh)[i4];
    float f[4] = {v.x, v.y, v.z, v.w};
    int nm = n % 31;
    unsigned short o[4];
    #pragma unroll
    for (int t = 0; t < 4; t++)
        o[t] = (nm >= ((k0 + t) % 31)) ? f2bf(f[t]) : (unsigned short)0;
    ushort4 s = {o[0], o[1], o[2], o[3]};
    ((ushort4*)Wb)[i4] = s;
}

// ---- layer 0: a1[b,h] = relu(sum_{k<=h%31} x[b,k]*W0[h,k] + b0[h]) -> bf16 ----
__global__ void layer0_kernel(const float* __restrict__ x,
                              const float* __restrict__ W0,
                              const float* __restrict__ b0,
                              unsigned short* __restrict__ out) {
    int b = blockIdx.y;
    int h = blockIdx.x * 256 + threadIdx.x;
    __shared__ float xs[D_];
    if (threadIdx.x < D_) xs[threadIdx.x] = x[b * D_ + threadIdx.x];
    __syncthreads();
    int kmax = h % 31;
    float acc = b0[h];
    const float* wr = W0 + (size_t)h * D_;
    for (int k = 0; k <= kmax; k++) acc = fmaf(xs[k], wr[k], acc);
    out[(size_t)b * H_ + h] = f2bf(fmaxf(acc, 0.f));
}

// ---- hidden GEMM: C[4096,1024] = relu(A @ Wb^T + bias), bf16 in/out, fp32 acc ----
// Tile 128(M) x 64(N) x 32(K). 4 waves, each 64x32 via 4x2 accs of 16x16x32 MFMA.
#define TM 128
#define TN 64
#define TK 32

__global__ __launch_bounds__(256, 2) void gemm_bf16_mfma(
        const unsigned short* __restrict__ A,
        const unsigned short* __restrict__ Wb,
        const float* __restrict__ bias,
        unsigned short* __restrict__ C) {
    __shared__ unsigned short sA[TM * TK];   // [row][k] row-major, row stride 32 elem (64B)
    __shared__ unsigned short sB[TN * TK];
    const int tid = threadIdx.x;
    const int wave = tid >> 6, lane = tid & 63;
    const int mBase = blockIdx.y * TM, nBase = blockIdx.x * TN;
    const int wm = wave >> 1, wn = wave & 1;

    // staging: each 1KB segment = 16 rows; lane covers row seg*16 + lane/4, k-octet lane%4
    const int srow = lane >> 2;
    const int koct = lane & 3;
    const unsigned short* gA0 = A  + (size_t)(mBase + wave * 32 + srow) * H_ + koct * 8;
    const unsigned short* gA1 = gA0 + 16 * H_;
    const unsigned short* gB  = Wb + (size_t)(nBase + wave * 16 + srow) * H_ + koct * 8;
    unsigned short* lA0 = sA + (wave * 2 + 0) * 512;
    unsigned short* lA1 = sA + (wave * 2 + 1) * 512;
    unsigned short* lB  = sB + wave * 512;

    // fragment offsets: A[m=lane&15][k=(lane>>4)*8+j], B[n=lane&15][k=...]
    const int frow = lane & 15;
    const int fk = lane >> 4;
    int offA[4], offB[2];
    #pragma unroll
    for (int i = 0; i < 4; i++) offA[i] = (wm * 64 + i * 16 + frow) * TK + fk * 8;
    #pragma unroll
    for (int j = 0; j < 2; j++) offB[j] = (wn * 32 + j * 16 + frow) * TK + fk * 8;

    floatx4 acc[4][2] = {};

    for (int k0 = 0; k0 < H_; k0 += TK) {
        glds16(gA0 + k0, lA0);
        glds16(gA1 + k0, lA1);
        glds16(gB  + k0, lB);
        __syncthreads();                      // waits vmcnt(0): staging visible
        short8 av[4], bv[2];
        #pragma unroll
        for (int i = 0; i < 4; i++) av[i] = *(const short8*)(sA + offA[i]);
        #pragma unroll
        for (int j = 0; j < 2; j++) bv[j] = *(const short8*)(sB + offB[j]);
        #pragma unroll
        for (int i = 0; i < 4; i++)
            #pragma unroll
            for (int j = 0; j < 2; j++)
                acc[i][j] = __builtin_amdgcn_mfma_f32_16x16x32_bf16(av[i], bv[j], acc[i][j], 0, 0, 0);
        __syncthreads();                      // compute done before next overwrite
    }

    // epilogue: C/D layout col(n)=lane&15, row(m)=(lane>>4)*4+reg
    const int col0 = nBase + wn * 32 + frow;
    const float bia[2] = {bias[col0], bias[col0 + 16]};
    #pragma unroll
    for (int i = 0; i < 4; i++) {
        const int rowb = mBase + wm * 64 + i * 16 + fk * 4;
        #pragma unroll
        for (int j = 0; j < 2; j++) {
            const int col = col0 + j * 16;
            #pragma unroll
            for (int r = 0; r < 4; r++) {
                float v = fmaxf(acc[i][j][r] + bia[j], 0.f);
                C[(size_t)(rowb + r) * H_ + col] = f2bf(v);
            }
        }
    }
}

// ---- output step: theta cols idx / idx+32, update x[:,idx] ----
__global__ void out_step_kernel(const unsigned short* __restrict__ a,
                                const float* __restrict__ Wout,
                                const float* __restrict__ bout,
                                const float* __restrict__ z,
                                float* __restrict__ x,
                                int idx) {
    int lane = threadIdx.x & 63;
    int b = blockIdx.x * 4 + (threadIdx.x >> 6);
    const unsigned short* ar = a + (size_t)b * H_;
    const float* wmu = Wout + (size_t)idx * H_;
    const float* wls = Wout + (size_t)(idx + D_) * H_;
    int h0 = lane * 16;
    union { uint4 v[2]; unsigned short s[16]; } u;
    u.v[0] = ((const uint4*)(ar + h0))[0];
    u.v[1] = ((const uint4*)(ar + h0))[1];
    float smu = 0.f, sls = 0.f;
    #pragma unroll
    for (int t = 0; t < 16; t++) {
        int h = h0 + t;
        if ((h % 31) < idx) {            // mask: d_hid[h] <= idx-1
            float av = bf2f(u.s[t]);
            smu = fmaf(av, wmu[h], smu);
            sls = fmaf(av, wls[h], sls);
        }
    }
    #pragma unroll
    for (int off = 32; off > 0; off >>= 1) {
        smu += __shfl_down(smu, off);
        sls += __shfl_down(sls, off);
    }
    if (lane == 0) {
        float mu = smu + bout[idx];
        float ls = sls + bout[idx + D_];
        x[(size_t)b * D_ + idx] = fmaf(z[(size_t)b * D_ + idx], expf(ls), mu);
    }
}

extern "C" void kernel_launch(void* const* d_in, const int* in_sizes, int n_in,
                              void* d_out, int out_size, void* d_ws, size_t ws_size,
                              hipStream_t stream) {
    const float* z    = (const float*)d_in[0];
    const float* W0   = (const float*)d_in[1];
    const float* b0   = (const float*)d_in[2];
    const float* Wh   = (const float*)d_in[3];   // [2, H, H]
    const float* bh   = (const float*)d_in[4];   // [2, H]
    const float* Wout = (const float*)d_in[5];   // [64, H]
    const float* bout = (const float*)d_in[6];   // [64]

    float* x = (float*)d_out;                    // [B, D] running state / output
    unsigned short* Wb = (unsigned short*)d_ws;  // [2, H, H] masked bf16
    unsigned short* a1 = Wb + 2 * H_ * H_;       // [B, H] bf16
    unsigned short* a2 = a1 + (size_t)B_ * H_;   // [B, H] bf16

    hipMemsetAsync(d_out, 0, (size_t)B_ * D_ * sizeof(float), stream);
    convert_wh<<<2 * H_ * H_ / 4 / 256, 256, 0, stream>>>(Wh, Wb);

    dim3 blk(256);
    dim3 g0(H_ / 256, B_);
    dim3 gg(H_ / TN, B_ / TM);    // (16, 32) = 512 blocks
    dim3 go(B_ / 4);

    for (int idx = 0; idx < D_; idx++) {
        layer0_kernel<<<g0, blk, 0, stream>>>(x, W0, b0, a1);
        gemm_bf16_mfma<<<gg, blk, 0, stream>>>(a1, Wb,             bh,      a2);
        gemm_bf16_mfma<<<gg, blk, 0, stream>>>(a2, Wb + H_ * H_,   bh + H_, a1);
        out_step_kernel<<<go, blk, 0, stream>>>(a1, Wout, bout, z, x, idx);
    }
}

// Round 3
// 1987.193 us; speedup vs baseline: 4.9385x; 1.6616x over previous
//
#include <hip/hip_runtime.h>
#include <hip/hip_bf16.h>

#define B_ 4096
#define D_ 32
#define H_ 1024

typedef __attribute__((ext_vector_type(8))) short short8;
typedef __attribute__((ext_vector_type(4))) float floatx4;

__device__ inline unsigned short f2bf(float f) {      // fp32 -> bf16 bits, RNE
    unsigned u = __float_as_uint(f);
    unsigned r = (u + 0x7FFF + ((u >> 16) & 1)) >> 16;
    return (unsigned short)r;
}
__device__ inline float bf2f(unsigned short b) {
    return __uint_as_float(((unsigned)b) << 16);
}

__device__ inline void glds16(const void* g, void* l) {
    __builtin_amdgcn_global_load_lds(
        (const __attribute__((address_space(1))) unsigned int*)g,
        (__attribute__((address_space(3))) unsigned int*)l, 16, 0, 0);
}

// ---- prep: Wh[2,H,H] fp32 -> masked bf16.  mask(n,k) = (n%31 >= k%31) ----
__global__ void convert_wh(const float* __restrict__ Wh, unsigned short* __restrict__ Wb) {
    int i4 = blockIdx.x * 256 + threadIdx.x;       // float4 group over 2*H*H
    int n = (i4 >> 8) & 1023;                      // 256 float4 per K-row
    int k0 = (i4 & 255) * 4;
    const float4 v = ((const float4*)Wh)[i4];
    float f[4] = {v.x, v.y, v.z, v.w};
    int nm = n % 31;
    unsigned short o[4];
    #pragma unroll
    for (int t = 0; t < 4; t++)
        o[t] = (nm >= ((k0 + t) % 31)) ? f2bf(f[t]) : (unsigned short)0;
    ushort4 s = {o[0], o[1], o[2], o[3]};
    ((ushort4*)Wb)[i4] = s;
}

// ---- prep: W0[H,32] fp32 -> masked bf16.  mask(h,k) = (h%31 >= k) ----
__global__ void convert_w0(const float* __restrict__ W0, unsigned short* __restrict__ W0b) {
    int i4 = blockIdx.x * 256 + threadIdx.x;       // float4 group over H*32
    int h = i4 >> 3;                               // 8 float4 per row
    int k0 = (i4 & 7) * 4;
    const float4 v = ((const float4*)W0)[i4];
    float f[4] = {v.x, v.y, v.z, v.w};
    int hm = h % 31;
    unsigned short o[4];
    #pragma unroll
    for (int t = 0; t < 4; t++)
        o[t] = (hm >= k0 + t) ? f2bf(f[t]) : (unsigned short)0;
    ushort4 s = {o[0], o[1], o[2], o[3]};
    ((ushort4*)W0b)[i4] = s;
}

// ---- layer 0 as MFMA GEMM: a1 = relu(xb @ W0b^T + b0).  M=4096,N=1024,K=32 ----
// Tile 128x64, K=32 in one shot: A tile = contiguous 8KB, B tile = contiguous 4KB.
__global__ __launch_bounds__(256, 2) void layer0_mfma(
        const unsigned short* __restrict__ xb,
        const unsigned short* __restrict__ W0b,
        const float* __restrict__ b0,
        unsigned short* __restrict__ C) {
    __shared__ unsigned short sAB[12 * 512];       // sA = 128x32 (8 seg), sB = 64x32 (4 seg)
    const int tid = threadIdx.x;
    const int wave = tid >> 6, lane = tid & 63;
    const int mBase = blockIdx.y * 128, nBase = blockIdx.x * 64;
    const int wm = wave >> 1, wn = wave & 1;

    // stage 12 x 1KB segments; wave w takes segments 3w..3w+2 (lane-contiguous 16B each)
    #pragma unroll
    for (int s = 0; s < 3; s++) {
        int seg = wave * 3 + s;
        const unsigned short* src = (seg < 8)
            ? xb  + (size_t)mBase * 32 + seg * 512 + lane * 8
            : W0b + (size_t)nBase * 32 + (seg - 8) * 512 + lane * 8;
        glds16(src, sAB + seg * 512);
    }
    __syncthreads();

    const unsigned short* sA = sAB;
    const unsigned short* sB = sAB + 8 * 512;
    const int frow = lane & 15;
    const int fk = lane >> 4;
    floatx4 acc[4][2] = {};
    short8 bv[2];
    #pragma unroll
    for (int j = 0; j < 2; j++)
        bv[j] = *(const short8*)(sB + (wn * 32 + j * 16 + frow) * 32 + fk * 8);
    #pragma unroll
    for (int i = 0; i < 4; i++) {
        short8 av = *(const short8*)(sA + (wm * 64 + i * 16 + frow) * 32 + fk * 8);
        #pragma unroll
        for (int j = 0; j < 2; j++)
            acc[i][j] = __builtin_amdgcn_mfma_f32_16x16x32_bf16(av, bv[j], acc[i][j], 0, 0, 0);
    }

    const int col0 = nBase + wn * 32 + frow;
    const float bia[2] = {b0[col0], b0[col0 + 16]};
    #pragma unroll
    for (int i = 0; i < 4; i++) {
        const int rowb = mBase + wm * 64 + i * 16 + fk * 4;
        #pragma unroll
        for (int j = 0; j < 2; j++) {
            const int col = col0 + j * 16;
            #pragma unroll
            for (int r = 0; r < 4; r++)
                C[(size_t)(rowb + r) * H_ + col] = f2bf(fmaxf(acc[i][j][r] + bia[j], 0.f));
        }
    }
}

// ---- hidden GEMM: C[4096,1024] = relu(A @ Wb^T + bias), bf16 in/out, fp32 acc ----
#define TM 128
#define TN 64
#define TK 32

__global__ __launch_bounds__(256, 2) void gemm_bf16_mfma(
        const unsigned short* __restrict__ A,
        const unsigned short* __restrict__ Wb,
        const float* __restrict__ bias,
        unsigned short* __restrict__ C) {
    __shared__ unsigned short sA[TM * TK];   // [row][k] row-major, row stride 32 elem (64B)
    __shared__ unsigned short sB[TN * TK];
    const int tid = threadIdx.x;
    const int wave = tid >> 6, lane = tid & 63;
    const int mBase = blockIdx.y * TM, nBase = blockIdx.x * TN;
    const int wm = wave >> 1, wn = wave & 1;

    const int srow = lane >> 2;
    const int koct = lane & 3;
    const unsigned short* gA0 = A  + (size_t)(mBase + wave * 32 + srow) * H_ + koct * 8;
    const unsigned short* gA1 = gA0 + 16 * H_;
    const unsigned short* gB  = Wb + (size_t)(nBase + wave * 16 + srow) * H_ + koct * 8;
    unsigned short* lA0 = sA + (wave * 2 + 0) * 512;
    unsigned short* lA1 = sA + (wave * 2 + 1) * 512;
    unsigned short* lB  = sB + wave * 512;

    const int frow = lane & 15;
    const int fk = lane >> 4;
    int offA[4], offB[2];
    #pragma unroll
    for (int i = 0; i < 4; i++) offA[i] = (wm * 64 + i * 16 + frow) * TK + fk * 8;
    #pragma unroll
    for (int j = 0; j < 2; j++) offB[j] = (wn * 32 + j * 16 + frow) * TK + fk * 8;

    floatx4 acc[4][2] = {};

    for (int k0 = 0; k0 < H_; k0 += TK) {
        glds16(gA0 + k0, lA0);
        glds16(gA1 + k0, lA1);
        glds16(gB  + k0, lB);
        __syncthreads();
        short8 av[4], bv[2];
        #pragma unroll
        for (int i = 0; i < 4; i++) av[i] = *(const short8*)(sA + offA[i]);
        #pragma unroll
        for (int j = 0; j < 2; j++) bv[j] = *(const short8*)(sB + offB[j]);
        #pragma unroll
        for (int i = 0; i < 4; i++)
            #pragma unroll
            for (int j = 0; j < 2; j++)
                acc[i][j] = __builtin_amdgcn_mfma_f32_16x16x32_bf16(av[i], bv[j], acc[i][j], 0, 0, 0);
        __syncthreads();
    }

    const int col0 = nBase + wn * 32 + frow;
    const float bia[2] = {bias[col0], bias[col0 + 16]};
    #pragma unroll
    for (int i = 0; i < 4; i++) {
        const int rowb = mBase + wm * 64 + i * 16 + fk * 4;
        #pragma unroll
        for (int j = 0; j < 2; j++) {
            const int col = col0 + j * 16;
            #pragma unroll
            for (int r = 0; r < 4; r++) {
                float v = fmaxf(acc[i][j][r] + bia[j], 0.f);
                C[(size_t)(rowb + r) * H_ + col] = f2bf(v);
            }
        }
    }
}

// ---- output step: theta cols idx / idx+32, update x[:,idx] and xb[:,idx] ----
__global__ void out_step_kernel(const unsigned short* __restrict__ a,
                                const float* __restrict__ Wout,
                                const float* __restrict__ bout,
                                const float* __restrict__ z,
                                float* __restrict__ x,
                                unsigned short* __restrict__ xb,
                                int idx) {
    int lane = threadIdx.x & 63;
    int b = blockIdx.x * 4 + (threadIdx.x >> 6);
    const unsigned short* ar = a + (size_t)b * H_;
    const float* wmu = Wout + (size_t)idx * H_;
    const float* wls = Wout + (size_t)(idx + D_) * H_;
    int h0 = lane * 16;
    union { uint4 v[2]; unsigned short s[16]; } u;
    u.v[0] = ((const uint4*)(ar + h0))[0];
    u.v[1] = ((const uint4*)(ar + h0))[1];
    float smu = 0.f, sls = 0.f;
    #pragma unroll
    for (int t = 0; t < 16; t++) {
        int h = h0 + t;
        if ((h % 31) < idx) {            // mask: d_hid[h] <= idx-1
            float av = bf2f(u.s[t]);
            smu = fmaf(av, wmu[h], smu);
            sls = fmaf(av, wls[h], sls);
        }
    }
    #pragma unroll
    for (int off = 32; off > 0; off >>= 1) {
        smu += __shfl_down(smu, off);
        sls += __shfl_down(sls, off);
    }
    if (lane == 0) {
        float mu = smu + bout[idx];
        float ls = sls + bout[idx + D_];
        float xi = fmaf(z[(size_t)b * D_ + idx], expf(ls), mu);
        x[(size_t)b * D_ + idx] = xi;
        xb[(size_t)b * D_ + idx] = f2bf(xi);
    }
}

extern "C" void kernel_launch(void* const* d_in, const int* in_sizes, int n_in,
                              void* d_out, int out_size, void* d_ws, size_t ws_size,
                              hipStream_t stream) {
    const float* z    = (const float*)d_in[0];
    const float* W0   = (const float*)d_in[1];
    const float* b0   = (const float*)d_in[2];
    const float* Wh   = (const float*)d_in[3];   // [2, H, H]
    const float* bh   = (const float*)d_in[4];   // [2, H]
    const float* Wout = (const float*)d_in[5];   // [64, H]
    const float* bout = (const float*)d_in[6];   // [64]

    float* x = (float*)d_out;                    // [B, D] running state / output
    unsigned short* Wb  = (unsigned short*)d_ws;       // [2, H, H] masked bf16
    unsigned short* W0b = Wb + 2 * H_ * H_;            // [H, 32] masked bf16
    unsigned short* a1  = W0b + H_ * D_;               // [B, H] bf16
    unsigned short* a2  = a1 + (size_t)B_ * H_;        // [B, H] bf16
    unsigned short* xb  = a2 + (size_t)B_ * H_;        // [B, D] bf16 running state

    hipMemsetAsync(d_out, 0, (size_t)B_ * D_ * sizeof(float), stream);
    hipMemsetAsync(xb, 0, (size_t)B_ * D_ * sizeof(unsigned short), stream);
    convert_wh<<<2 * H_ * H_ / 4 / 256, 256, 0, stream>>>(Wh, Wb);
    convert_w0<<<H_ * D_ / 4 / 256, 256, 0, stream>>>(W0, W0b);

    dim3 blk(256);
    dim3 gl0(H_ / 64, B_ / 128);  // (16, 32)
    dim3 gg(H_ / TN, B_ / TM);    // (16, 32) = 512 blocks
    dim3 go(B_ / 4);

    for (int idx = 0; idx < D_; idx++) {
        layer0_mfma<<<gl0, blk, 0, stream>>>(xb, W0b, b0, a1);
        gemm_bf16_mfma<<<gg, blk, 0, stream>>>(a1, Wb,             bh,      a2);
        gemm_bf16_mfma<<<gg, blk, 0, stream>>>(a2, Wb + H_ * H_,   bh + H_, a1);
        out_step_kernel<<<go, blk, 0, stream>>>(a1, Wout, bout, z, x, xb, idx);
    }
}

// Round 4
// 1171.395 us; speedup vs baseline: 8.3778x; 1.6964x over previous
//
#include <hip/hip_runtime.h>
#include <hip/hip_bf16.h>

#define B_ 4096
#define D_ 32
#define H_ 1024

typedef __attribute__((ext_vector_type(8))) short short8;
typedef __attribute__((ext_vector_type(4))) float floatx4;

__device__ inline unsigned short f2bf(float f) {      // fp32 -> bf16 bits, RNE
    unsigned u = __float_as_uint(f);
    unsigned r = (u + 0x7FFF + ((u >> 16) & 1)) >> 16;
    return (unsigned short)r;
}
__device__ inline float bf2f(unsigned short b) {
    return __uint_as_float(((unsigned)b) << 16);
}
__device__ inline void glds16(const void* g, void* l) {
    __builtin_amdgcn_global_load_lds(
        (const __attribute__((address_space(1))) unsigned int*)g,
        (__attribute__((address_space(3))) unsigned int*)l, 16, 0, 0);
}

// degree-sorted order: degree 0 -> slots [0,34), degree d>=1 -> slots [34+33(d-1), 34+33d)
__device__ inline int degs(int hp) { return (hp < 34) ? 0 : (hp - 1) / 33; }
__device__ inline int permf(int hp) {                  // sorted slot -> original h
    int d = degs(hp);
    int r = d ? (hp - 33 * d - 1) : hp;
    return d + 31 * r;
}

// ---- prep: Wh[2,H,H] -> permuted+masked bf16 Wbp[l][n'][k'] ----
__global__ void convert_whp(const float* __restrict__ Wh, unsigned short* __restrict__ Wbp) {
    int t = blockIdx.x * 256 + threadIdx.x;        // over 2*1024*512 (2 k' per thread)
    int l = t >> 19;
    int np = (t >> 9) & 1023;
    int kp0 = (t & 511) * 2;
    int dn = degs(np);
    const float* src = Wh + ((size_t)l << 20) + ((size_t)permf(np) << 10);
    unsigned short o[2];
    #pragma unroll
    for (int j = 0; j < 2; j++) {
        int kp = kp0 + j;
        o[j] = (dn >= degs(kp)) ? f2bf(src[permf(kp)]) : (unsigned short)0;
    }
    *(ushort2*)(Wbp + ((size_t)l << 20) + ((size_t)np << 10) + kp0) = ushort2{o[0], o[1]};
}

// ---- prep: W0[H,32] -> permuted+masked bf16 W0bp[h'][k] ----
__global__ void convert_w0p(const float* __restrict__ W0, unsigned short* __restrict__ W0bp) {
    int t = blockIdx.x * 256 + threadIdx.x;        // over H*32
    int hp = t >> 5, k = t & 31;
    W0bp[t] = (degs(hp) >= k) ? f2bf(W0[permf(hp) * 32 + k]) : (unsigned short)0;
}

// ---- prep: Wout[64,H] -> permuted fp32 with zeroed tail per row ----
__global__ void convert_woutp(const float* __restrict__ Wout, float* __restrict__ Woutp) {
    int t = blockIdx.x * 256 + threadIdx.x;        // over 64*1024
    int r = t >> 10, hp = t & 1023;
    int m = r & 31;
    int ns = m ? (33 * m + 1) : 0;                 // live-prefix length at step m
    Woutp[t] = (hp < ns) ? Wout[r * 1024 + permf(hp)] : 0.f;
}

// ---- prep: permuted biases ----
__global__ void convert_bias(const float* __restrict__ b0, const float* __restrict__ bh,
                             float* __restrict__ b0p, float* __restrict__ bhp) {
    int t = blockIdx.x * 256 + threadIdx.x;        // over 3*1024
    int hp = t & 1023;
    int p = permf(hp);
    if (t < 1024) b0p[hp] = b0[p];
    else if (t < 2048) bhp[hp] = bh[p];
    else bhp[1024 + hp] = bh[1024 + p];
}

// ---- layer 0 as MFMA GEMM: a1[:, :Nr] = relu(xb @ W0bp^T + b0p).  K=32 one-shot ----
__global__ __launch_bounds__(256, 2) void layer0_mfma(
        const unsigned short* __restrict__ xb,
        const unsigned short* __restrict__ W0b,
        const float* __restrict__ b0,
        unsigned short* __restrict__ C) {
    __shared__ unsigned short sAB[12 * 512];       // sA = 128x32 (8 seg), sB = 64x32 (4 seg)
    const int tid = threadIdx.x;
    const int wave = tid >> 6, lane = tid & 63;
    const int mBase = blockIdx.y * 128, nBase = blockIdx.x * 64;
    const int wm = wave >> 1, wn = wave & 1;

    #pragma unroll
    for (int s = 0; s < 3; s++) {
        int seg = wave * 3 + s;
        const unsigned short* src = (seg < 8)
            ? xb  + (size_t)mBase * 32 + seg * 512 + lane * 8
            : W0b + (size_t)nBase * 32 + (seg - 8) * 512 + lane * 8;
        glds16(src, sAB + seg * 512);
    }
    __syncthreads();

    const unsigned short* sA = sAB;
    const unsigned short* sB = sAB + 8 * 512;
    const int frow = lane & 15;
    const int fk = lane >> 4;
    floatx4 acc[4][2] = {};
    short8 bv[2];
    #pragma unroll
    for (int j = 0; j < 2; j++)
        bv[j] = *(const short8*)(sB + (wn * 32 + j * 16 + frow) * 32 + fk * 8);
    #pragma unroll
    for (int i = 0; i < 4; i++) {
        short8 av = *(const short8*)(sA + (wm * 64 + i * 16 + frow) * 32 + fk * 8);
        #pragma unroll
        for (int j = 0; j < 2; j++)
            acc[i][j] = __builtin_amdgcn_mfma_f32_16x16x32_bf16(av, bv[j], acc[i][j], 0, 0, 0);
    }

    const int col0 = nBase + wn * 32 + frow;
    const float bia[2] = {b0[col0], b0[col0 + 16]};
    #pragma unroll
    for (int i = 0; i < 4; i++) {
        const int rowb = mBase + wm * 64 + i * 16 + fk * 4;
        #pragma unroll
        for (int j = 0; j < 2; j++) {
            const int col = col0 + j * 16;
            #pragma unroll
            for (int r = 0; r < 4; r++)
                C[(size_t)(rowb + r) * H_ + col] = f2bf(fmaxf(acc[i][j][r] + bia[j], 0.f));
        }
    }
}

// ---- hidden GEMM: C[:, :Nr] = relu(A[:, :Kr] @ Wbp[:Nr, :Kr]^T + bias), runtime Kr ----
#define TM 128
#define TN 64
#define TK 32

__global__ __launch_bounds__(256, 2) void gemm_bf16_mfma(
        const unsigned short* __restrict__ A,
        const unsigned short* __restrict__ Wb,
        const float* __restrict__ bias,
        unsigned short* __restrict__ C,
        int Kr) {
    __shared__ unsigned short sA[TM * TK];
    __shared__ unsigned short sB[TN * TK];
    const int tid = threadIdx.x;
    const int wave = tid >> 6, lane = tid & 63;
    const int mBase = blockIdx.y * TM, nBase = blockIdx.x * TN;
    const int wm = wave >> 1, wn = wave & 1;

    const int srow = lane >> 2;
    const int koct = lane & 3;
    const unsigned short* gA0 = A  + (size_t)(mBase + wave * 32 + srow) * H_ + koct * 8;
    const unsigned short* gA1 = gA0 + 16 * H_;
    const unsigned short* gB  = Wb + (size_t)(nBase + wave * 16 + srow) * H_ + koct * 8;
    unsigned short* lA0 = sA + (wave * 2 + 0) * 512;
    unsigned short* lA1 = sA + (wave * 2 + 1) * 512;
    unsigned short* lB  = sB + wave * 512;

    const int frow = lane & 15;
    const int fk = lane >> 4;
    int offA[4], offB[2];
    #pragma unroll
    for (int i = 0; i < 4; i++) offA[i] = (wm * 64 + i * 16 + frow) * TK + fk * 8;
    #pragma unroll
    for (int j = 0; j < 2; j++) offB[j] = (wn * 32 + j * 16 + frow) * TK + fk * 8;

    floatx4 acc[4][2] = {};

    for (int k0 = 0; k0 < Kr; k0 += TK) {
        glds16(gA0 + k0, lA0);
        glds16(gA1 + k0, lA1);
        glds16(gB  + k0, lB);
        __syncthreads();
        short8 av[4], bv[2];
        #pragma unroll
        for (int i = 0; i < 4; i++) av[i] = *(const short8*)(sA + offA[i]);
        #pragma unroll
        for (int j = 0; j < 2; j++) bv[j] = *(const short8*)(sB + offB[j]);
        #pragma unroll
        for (int i = 0; i < 4; i++)
            #pragma unroll
            for (int j = 0; j < 2; j++)
                acc[i][j] = __builtin_amdgcn_mfma_f32_16x16x32_bf16(av[i], bv[j], acc[i][j], 0, 0, 0);
        __syncthreads();
    }

    const int col0 = nBase + wn * 32 + frow;
    const float bia[2] = {bias[col0], bias[col0 + 16]};
    #pragma unroll
    for (int i = 0; i < 4; i++) {
        const int rowb = mBase + wm * 64 + i * 16 + fk * 4;
        #pragma unroll
        for (int j = 0; j < 2; j++) {
            const int col = col0 + j * 16;
            #pragma unroll
            for (int r = 0; r < 4; r++) {
                float v = fmaxf(acc[i][j][r] + bia[j], 0.f);
                C[(size_t)(rowb + r) * H_ + col] = f2bf(v);
            }
        }
    }
}

// ---- output step: theta cols idx / idx+32 via pre-masked Woutp; update x, xb ----
__global__ void out_step_kernel(const unsigned short* __restrict__ a,
                                const float* __restrict__ Woutp,
                                const float* __restrict__ bout,
                                const float* __restrict__ z,
                                float* __restrict__ x,
                                unsigned short* __restrict__ xb,
                                int idx) {
    int lane = threadIdx.x & 63;
    int b = blockIdx.x * 4 + (threadIdx.x >> 6);
    const unsigned short* ar = a + (size_t)b * H_;
    const float* wmu = Woutp + (size_t)idx * H_;
    const float* wls = Woutp + (size_t)(idx + D_) * H_;
    int h0 = lane * 16;
    union { uint4 v[2]; unsigned short s[16]; } u;
    u.v[0] = ((const uint4*)(ar + h0))[0];
    u.v[1] = ((const uint4*)(ar + h0))[1];
    float smu = 0.f, sls = 0.f;
    #pragma unroll
    for (int t = 0; t < 16; t++) {
        float av = bf2f(u.s[t]);               // masked weights are exactly 0 beyond prefix
        smu = fmaf(av, wmu[h0 + t], smu);
        sls = fmaf(av, wls[h0 + t], sls);
    }
    #pragma unroll
    for (int off = 32; off > 0; off >>= 1) {
        smu += __shfl_down(smu, off);
        sls += __shfl_down(sls, off);
    }
    if (lane == 0) {
        float mu = smu + bout[idx];
        float ls = sls + bout[idx + D_];
        float xi = fmaf(z[(size_t)b * D_ + idx], expf(ls), mu);
        x[(size_t)b * D_ + idx] = xi;
        xb[(size_t)b * D_ + idx] = f2bf(xi);
    }
}

extern "C" void kernel_launch(void* const* d_in, const int* in_sizes, int n_in,
                              void* d_out, int out_size, void* d_ws, size_t ws_size,
                              hipStream_t stream) {
    const float* z    = (const float*)d_in[0];
    const float* W0   = (const float*)d_in[1];
    const float* b0   = (const float*)d_in[2];
    const float* Wh   = (const float*)d_in[3];   // [2, H, H]
    const float* bh   = (const float*)d_in[4];   // [2, H]
    const float* Wout = (const float*)d_in[5];   // [64, H]
    const float* bout = (const float*)d_in[6];   // [64]

    float* x = (float*)d_out;                          // [B, D] running state / output
    unsigned short* Wbp  = (unsigned short*)d_ws;      // [2, H, H] permuted+masked bf16
    unsigned short* W0bp = Wbp + 2 * H_ * H_;          // [H, 32]
    unsigned short* a1   = W0bp + H_ * D_;             // [B, H] bf16 (degree-sorted)
    unsigned short* a2   = a1 + (size_t)B_ * H_;       // [B, H]
    unsigned short* xb   = a2 + (size_t)B_ * H_;       // [B, D] bf16 running state
    float* b0p   = (float*)(xb + (size_t)B_ * D_);     // [H]
    float* bhp   = b0p + H_;                           // [2, H]
    float* Woutp = bhp + 2 * H_;                       // [64, H] permuted, tail-zeroed

    hipMemsetAsync(d_out, 0, (size_t)B_ * D_ * sizeof(float), stream);
    hipMemsetAsync(xb, 0, (size_t)B_ * D_ * sizeof(unsigned short), stream);
    convert_whp<<<2 * H_ * H_ / 2 / 256, 256, 0, stream>>>(Wh, Wbp);
    convert_w0p<<<H_ * D_ / 256, 256, 0, stream>>>(W0, W0bp);
    convert_woutp<<<64 * H_ / 256, 256, 0, stream>>>(Wout, Woutp);
    convert_bias<<<3 * H_ / 256, 256, 0, stream>>>(b0, bh, b0p, bhp);

    dim3 blk(256);
    dim3 go(B_ / 4);

    for (int idx = 0; idx < D_; idx++) {
        if (idx > 0) {
            int n = 33 * idx + 1;                      // live prefix length
            int Nr = (n + 63) & ~63;
            if (Nr > H_) Nr = H_;
            dim3 gl(Nr / 64, B_ / 128);
            layer0_mfma<<<gl, blk, 0, stream>>>(xb, W0bp, b0p, a1);
            dim3 gg(Nr / TN, B_ / TM);
            gemm_bf16_mfma<<<gg, blk, 0, stream>>>(a1, Wbp,            bhp,      a2, Nr);
            gemm_bf16_mfma<<<gg, blk, 0, stream>>>(a2, Wbp + H_ * H_,  bhp + H_, a1, Nr);
        }
        out_step_kernel<<<go, blk, 0, stream>>>(a1, Woutp, bout, z, x, xb, idx);
    }
}

// Round 5
// 1078.205 us; speedup vs baseline: 9.1019x; 1.0864x over previous
//
#include <hip/hip_runtime.h>
#include <hip/hip_bf16.h>

#define B_ 4096
#define D_ 32
#define H_ 1024

typedef __attribute__((ext_vector_type(8))) short short8;
typedef __attribute__((ext_vector_type(4))) float floatx4;

__device__ inline unsigned short f2bf(float f) {      // fp32 -> bf16 bits, RNE
    unsigned u = __float_as_uint(f);
    unsigned r = (u + 0x7FFF + ((u >> 16) & 1)) >> 16;
    return (unsigned short)r;
}
__device__ inline float bf2f(unsigned short b) {
    return __uint_as_float(((unsigned)b) << 16);
}
__device__ inline void glds16(const void* g, void* l) {
    __builtin_amdgcn_global_load_lds(
        (const __attribute__((address_space(1))) unsigned int*)g,
        (__attribute__((address_space(3))) unsigned int*)l, 16, 0, 0);
}

// degree-sorted order: degree 0 -> slots [0,34), degree d>=1 -> slots [33d+1, 33d+34)
__device__ inline int degs(int hp) { return (hp < 34) ? 0 : (hp - 1) / 33; }
__device__ inline int permf(int hp) {                  // sorted slot -> original h
    int d = degs(hp);
    int r = d ? (hp - 33 * d - 1) : hp;
    return d + 31 * r;
}

// ---- prep: Wh[2,H,H] -> permuted+masked bf16 Wbp[l][n'][k'] ----
__global__ void convert_whp(const float* __restrict__ Wh, unsigned short* __restrict__ Wbp) {
    int t = blockIdx.x * 256 + threadIdx.x;        // over 2*1024*512 (2 k' per thread)
    int l = t >> 19;
    int np = (t >> 9) & 1023;
    int kp0 = (t & 511) * 2;
    int dn = degs(np);
    const float* src = Wh + ((size_t)l << 20) + ((size_t)permf(np) << 10);
    unsigned short o[2];
    #pragma unroll
    for (int j = 0; j < 2; j++) {
        int kp = kp0 + j;
        o[j] = (dn >= degs(kp)) ? f2bf(src[permf(kp)]) : (unsigned short)0;
    }
    *(ushort2*)(Wbp + ((size_t)l << 20) + ((size_t)np << 10) + kp0) = ushort2{o[0], o[1]};
}

// ---- prep: W0[H,32] -> permuted+masked bf16 W0bp[h'][k] ----
__global__ void convert_w0p(const float* __restrict__ W0, unsigned short* __restrict__ W0bp) {
    int t = blockIdx.x * 256 + threadIdx.x;        // over H*32
    int hp = t >> 5, k = t & 31;
    W0bp[t] = (degs(hp) >= k) ? f2bf(W0[permf(hp) * 32 + k]) : (unsigned short)0;
}

// ---- prep: Wout[64,H] -> permuted fp32 with zeroed tail per row ----
__global__ void convert_woutp(const float* __restrict__ Wout, float* __restrict__ Woutp) {
    int t = blockIdx.x * 256 + threadIdx.x;        // over 64*1024
    int r = t >> 10, hp = t & 1023;
    int m = r & 31;
    int ns = m ? (33 * m + 1) : 0;                 // live-prefix length at step m
    Woutp[t] = (hp < ns) ? Wout[r * 1024 + permf(hp)] : 0.f;
}

// ---- prep: permuted biases ----
__global__ void convert_bias(const float* __restrict__ b0, const float* __restrict__ bh,
                             float* __restrict__ b0p, float* __restrict__ bhp) {
    int t = blockIdx.x * 256 + threadIdx.x;        // over 3*1024
    int hp = t & 1023;
    int p = permf(hp);
    if (t < 1024) b0p[hp] = b0[p];
    else if (t < 2048) bhp[hp] = bh[p];
    else bhp[1024 + hp] = bh[1024 + p];
}

// ---- layer 0 as MFMA GEMM: a1[:, :Nr] = relu(xb @ W0bp^T + b0p).  K=32 one-shot ----
__global__ __launch_bounds__(256, 2) void layer0_mfma(
        const unsigned short* __restrict__ xb,
        const unsigned short* __restrict__ W0b,
        const float* __restrict__ b0,
        unsigned short* __restrict__ C) {
    __shared__ unsigned short sAB[12 * 512];       // sA = 128x32 (8 seg), sB = 64x32 (4 seg)
    const int tid = threadIdx.x;
    const int wave = tid >> 6, lane = tid & 63;
    const int mBase = blockIdx.y * 128, nBase = blockIdx.x * 64;
    const int wm = wave >> 1, wn = wave & 1;

    #pragma unroll
    for (int s = 0; s < 3; s++) {
        int seg = wave * 3 + s;
        const unsigned short* src = (seg < 8)
            ? xb  + (size_t)mBase * 32 + seg * 512 + lane * 8
            : W0b + (size_t)nBase * 32 + (seg - 8) * 512 + lane * 8;
        glds16(src, sAB + seg * 512);
    }
    __syncthreads();

    const unsigned short* sA = sAB;
    const unsigned short* sB = sAB + 8 * 512;
    const int frow = lane & 15;
    const int fk = lane >> 4;
    floatx4 acc[4][2] = {};
    short8 bv[2];
    #pragma unroll
    for (int j = 0; j < 2; j++)
        bv[j] = *(const short8*)(sB + (wn * 32 + j * 16 + frow) * 32 + fk * 8);
    #pragma unroll
    for (int i = 0; i < 4; i++) {
        short8 av = *(const short8*)(sA + (wm * 64 + i * 16 + frow) * 32 + fk * 8);
        #pragma unroll
        for (int j = 0; j < 2; j++)
            acc[i][j] = __builtin_amdgcn_mfma_f32_16x16x32_bf16(av, bv[j], acc[i][j], 0, 0, 0);
    }

    const int col0 = nBase + wn * 32 + frow;
    const float bia[2] = {b0[col0], b0[col0 + 16]};
    #pragma unroll
    for (int i = 0; i < 4; i++) {
        const int rowb = mBase + wm * 64 + i * 16 + fk * 4;
        #pragma unroll
        for (int j = 0; j < 2; j++) {
            const int col = col0 + j * 16;
            #pragma unroll
            for (int r = 0; r < 4; r++)
                C[(size_t)(rowb + r) * H_ + col] = f2bf(fmaxf(acc[i][j][r] + bia[j], 0.f));
        }
    }
}

// ---- hidden GEMM, triangular: C[:, :Nr] = relu(A @ Wbp^T + bias) ----
// Tile 128(M) x 64(N) x BK=64 (two 32-panels). Per N-tile, K runs only to
// Klim(nb) = round64(33*degs(nb+63)+34): weights beyond are exactly zero.
#define TM 128
#define TN 64

__global__ __launch_bounds__(256, 2) void gemm_bf16_mfma(
        const unsigned short* __restrict__ A,
        const unsigned short* __restrict__ Wb,
        const float* __restrict__ bias,
        unsigned short* __restrict__ C,
        int Kr) {
    __shared__ unsigned short sA[TM * 64];   // two panels: [p][row][32], 8KB each
    __shared__ unsigned short sB[TN * 64];   // two panels: [p][row][32], 4KB each
    const int tid = threadIdx.x;
    const int wave = tid >> 6, lane = tid & 63;
    const int mBase = blockIdx.y * TM;
    const int nBase = (gridDim.x - 1 - blockIdx.x) * TN;   // long K-loops launch first
    const int wm = wave >> 1, wn = wave & 1;

    int nLast = nBase + 63;
    int dmax = (nLast < 34) ? 0 : (nLast - 1) / 33;
    int Klim = (33 * dmax + 34 + 63) & ~63;
    if (Klim > Kr) Klim = Kr;

    // staging: 24 segs of 512 shorts (16 rows x 32k each); wave w takes segs 6w..6w+5
    const unsigned short* gptr[6];
    unsigned short* lptr[6];
    const int srow = lane >> 2;            // 0..15
    const int koct = (lane & 3) * 8;       // 0,8,16,24
    #pragma unroll
    for (int s = 0; s < 6; s++) {
        int g = wave * 6 + s;
        if (g < 16) {                      // A: panel p=g>>3, seg g&7
            int p = g >> 3, s8 = g & 7;
            gptr[s] = A + (size_t)(mBase + s8 * 16 + srow) * H_ + p * 32 + koct;
            lptr[s] = sA + p * 4096 + s8 * 512;
        } else {                           // B: panel p=(g-16)>>2, seg (g-16)&3
            int h = g - 16, p = h >> 2, s4 = h & 3;
            gptr[s] = Wb + (size_t)(nBase + s4 * 16 + srow) * H_ + p * 32 + koct;
            lptr[s] = sB + p * 2048 + s4 * 512;
        }
    }

    const int frow = lane & 15;
    const int fk = lane >> 4;
    int offA[4], offB[2];
    #pragma unroll
    for (int i = 0; i < 4; i++) offA[i] = (wm * 64 + i * 16 + frow) * 32 + fk * 8;
    #pragma unroll
    for (int j = 0; j < 2; j++) offB[j] = (wn * 32 + j * 16 + frow) * 32 + fk * 8;

    floatx4 acc[4][2] = {};

    for (int k0 = 0; k0 < Klim; k0 += 64) {
        #pragma unroll
        for (int s = 0; s < 6; s++) glds16(gptr[s] + k0, lptr[s]);
        __syncthreads();
        #pragma unroll
        for (int c = 0; c < 2; c++) {
            short8 av[4], bv[2];
            #pragma unroll
            for (int i = 0; i < 4; i++) av[i] = *(const short8*)(sA + c * 4096 + offA[i]);
            #pragma unroll
            for (int j = 0; j < 2; j++) bv[j] = *(const short8*)(sB + c * 2048 + offB[j]);
            #pragma unroll
            for (int i = 0; i < 4; i++)
                #pragma unroll
                for (int j = 0; j < 2; j++)
                    acc[i][j] = __builtin_amdgcn_mfma_f32_16x16x32_bf16(av[i], bv[j], acc[i][j], 0, 0, 0);
        }
        __syncthreads();
    }

    const int col0 = nBase + wn * 32 + frow;
    const float bia[2] = {bias[col0], bias[col0 + 16]};
    #pragma unroll
    for (int i = 0; i < 4; i++) {
        const int rowb = mBase + wm * 64 + i * 16 + fk * 4;
        #pragma unroll
        for (int j = 0; j < 2; j++) {
            const int col = col0 + j * 16;
            #pragma unroll
            for (int r = 0; r < 4; r++) {
                float v = fmaxf(acc[i][j][r] + bia[j], 0.f);
                C[(size_t)(rowb + r) * H_ + col] = f2bf(v);
            }
        }
    }
}

// ---- output step: theta cols idx / idx+32 via pre-masked Woutp; update x, xb ----
__global__ void out_step_kernel(const unsigned short* __restrict__ a,
                                const float* __restrict__ Woutp,
                                const float* __restrict__ bout,
                                const float* __restrict__ z,
                                float* __restrict__ x,
                                unsigned short* __restrict__ xb,
                                int idx) {
    int lane = threadIdx.x & 63;
    int b = blockIdx.x * 4 + (threadIdx.x >> 6);
    const unsigned short* ar = a + (size_t)b * H_;
    const float* wmu = Woutp + (size_t)idx * H_;
    const float* wls = Woutp + (size_t)(idx + D_) * H_;
    int h0 = lane * 16;
    union { uint4 v[2]; unsigned short s[16]; } u;
    u.v[0] = ((const uint4*)(ar + h0))[0];
    u.v[1] = ((const uint4*)(ar + h0))[1];
    float smu = 0.f, sls = 0.f;
    #pragma unroll
    for (int t = 0; t < 16; t++) {
        float av = bf2f(u.s[t]);               // masked weights are exactly 0 beyond prefix
        smu = fmaf(av, wmu[h0 + t], smu);
        sls = fmaf(av, wls[h0 + t], sls);
    }
    #pragma unroll
    for (int off = 32; off > 0; off >>= 1) {
        smu += __shfl_down(smu, off);
        sls += __shfl_down(sls, off);
    }
    if (lane == 0) {
        float mu = smu + bout[idx];
        float ls = sls + bout[idx + D_];
        float xi = fmaf(z[(size_t)b * D_ + idx], expf(ls), mu);
        x[(size_t)b * D_ + idx] = xi;
        xb[(size_t)b * D_ + idx] = f2bf(xi);
    }
}

extern "C" void kernel_launch(void* const* d_in, const int* in_sizes, int n_in,
                              void* d_out, int out_size, void* d_ws, size_t ws_size,
                              hipStream_t stream) {
    const float* z    = (const float*)d_in[0];
    const float* W0   = (const float*)d_in[1];
    const float* b0   = (const float*)d_in[2];
    const float* Wh   = (const float*)d_in[3];   // [2, H, H]
    const float* bh   = (const float*)d_in[4];   // [2, H]
    const float* Wout = (const float*)d_in[5];   // [64, H]
    const float* bout = (const float*)d_in[6];   // [64]

    float* x = (float*)d_out;                          // [B, D] running state / output
    unsigned short* Wbp  = (unsigned short*)d_ws;      // [2, H, H] permuted+masked bf16
    unsigned short* W0bp = Wbp + 2 * H_ * H_;          // [H, 32]
    unsigned short* a1   = W0bp + H_ * D_;             // [B, H] bf16 (degree-sorted)
    unsigned short* a2   = a1 + (size_t)B_ * H_;       // [B, H]
    unsigned short* xb   = a2 + (size_t)B_ * H_;       // [B, D] bf16 running state
    float* b0p   = (float*)(xb + (size_t)B_ * D_);     // [H]
    float* bhp   = b0p + H_;                           // [2, H]
    float* Woutp = bhp + 2 * H_;                       // [64, H] permuted, tail-zeroed

    hipMemsetAsync(d_out, 0, (size_t)B_ * D_ * sizeof(float), stream);
    hipMemsetAsync(xb, 0, (size_t)B_ * D_ * sizeof(unsigned short), stream);
    convert_whp<<<2 * H_ * H_ / 2 / 256, 256, 0, stream>>>(Wh, Wbp);
    convert_w0p<<<H_ * D_ / 256, 256, 0, stream>>>(W0, W0bp);
    convert_woutp<<<64 * H_ / 256, 256, 0, stream>>>(Wout, Woutp);
    convert_bias<<<3 * H_ / 256, 256, 0, stream>>>(b0, bh, b0p, bhp);

    dim3 blk(256);
    dim3 go(B_ / 4);

    for (int idx = 0; idx < D_; idx++) {
        if (idx > 0) {
            int n = 33 * idx + 1;                      // live prefix length
            int Nr = (n + 63) & ~63;
            if (Nr > H_) Nr = H_;
            dim3 gl(Nr / 64, B_ / 128);
            layer0_mfma<<<gl, blk, 0, stream>>>(xb, W0bp, b0p, a1);
            dim3 gg(Nr / TN, B_ / TM);
            gemm_bf16_mfma<<<gg, blk, 0, stream>>>(a1, Wbp,            bhp,      a2, Nr);
            gemm_bf16_mfma<<<gg, blk, 0, stream>>>(a2, Wbp + H_ * H_,  bhp + H_, a1, Nr);
        }
        out_step_kernel<<<go, blk, 0, stream>>>(a1, Woutp, bout, z, x, xb, idx);
    }
}

// Round 6
// 429.731 us; speedup vs baseline: 22.8369x; 2.5090x over previous
//
#include <hip/hip_runtime.h>
#include <hip/hip_bf16.h>

#define B_ 4096
#define D_ 32
#define H_ 1024
#define AST 1032   // LDS activation row stride in shorts (pad 1024+8: conflict-free frags)

typedef __attribute__((ext_vector_type(8))) short short8;
typedef __attribute__((ext_vector_type(4))) float floatx4;

__device__ inline unsigned short f2bf(float f) {      // fp32 -> bf16 bits, RNE
    unsigned u = __float_as_uint(f);
    unsigned r = (u + 0x7FFF + ((u >> 16) & 1)) >> 16;
    return (unsigned short)r;
}
__device__ inline float bf2f(unsigned short b) {
    return __uint_as_float(((unsigned)b) << 16);
}

// degree-sorted order: degree 0 -> slots [0,34), degree d>=1 -> slots [33d+1, 33d+34)
__device__ inline int degs(int hp) { return (hp < 34) ? 0 : (hp - 1) / 33; }
__device__ inline int permf(int hp) {                  // sorted slot -> original h
    int d = degs(hp);
    int r = d ? (hp - 33 * d - 1) : hp;
    return d + 31 * r;
}

// ---- prep: Wh[2,H,H] -> permuted+masked bf16, staged through LDS (coalesced src reads) ----
__global__ __launch_bounds__(256) void convert_whp(const float* __restrict__ Wh,
                                                   unsigned short* __restrict__ Wbp) {
    __shared__ float row[H_];
    int l = blockIdx.x >> 10, np = blockIdx.x & 1023;
    int tid = threadIdx.x;
    const float* src = Wh + ((size_t)l << 20) + ((size_t)permf(np) << 10);
    ((float4*)row)[tid] = ((const float4*)src)[tid];
    __syncthreads();
    int dn = degs(np);
    unsigned short o[4];
    #pragma unroll
    for (int j = 0; j < 4; j++) {
        int kp = tid * 4 + j;
        o[j] = (dn >= degs(kp)) ? f2bf(row[permf(kp)]) : (unsigned short)0;
    }
    ((ushort4*)(Wbp + ((size_t)l << 20) + ((size_t)np << 10)))[tid] =
        ushort4{o[0], o[1], o[2], o[3]};
}

// ---- prep: W0[H,32] -> permuted+masked bf16 W0bp[h'][k] ----
__global__ void convert_w0p(const float* __restrict__ W0, unsigned short* __restrict__ W0bp) {
    int t = blockIdx.x * 256 + threadIdx.x;        // over H*32
    int hp = t >> 5, k = t & 31;
    W0bp[t] = (degs(hp) >= k) ? f2bf(W0[permf(hp) * 32 + k]) : (unsigned short)0;
}

// ---- prep: Wout[64,H] -> permuted fp32 with zeroed tail per row ----
__global__ void convert_woutp(const float* __restrict__ Wout, float* __restrict__ Woutp) {
    int t = blockIdx.x * 256 + threadIdx.x;        // over 64*1024
    int r = t >> 10, hp = t & 1023;
    int m = r & 31;
    int ns = m ? (33 * m + 1) : 0;                 // live-prefix length at step m
    Woutp[t] = (hp < ns) ? Wout[r * 1024 + permf(hp)] : 0.f;
}

// ---- prep: permuted biases ----
__global__ void convert_bias(const float* __restrict__ b0, const float* __restrict__ bh,
                             float* __restrict__ b0p, float* __restrict__ bhp) {
    int t = blockIdx.x * 256 + threadIdx.x;        // over 3*1024
    int hp = t & 1023;
    int p = permf(hp);
    if (t < 1024) b0p[hp] = b0[p];
    else if (t < 2048) bhp[hp] = bh[p];
    else bhp[1024 + hp] = bh[1024 + p];
}

// ---- band GEMM tile: one wave computes 16 band slots over nk K-chunks of 32 ----
// src: LDS activation buffer (rows 16 x AST). W: global [1024][1024] bf16 (masked).
// dst: LDS next-layer buffer. slot = this lane's output column (band slot).
__device__ inline void band_tile(const unsigned short* src, const unsigned short* __restrict__ W,
                                 const float* __restrict__ bias, unsigned short* dst,
                                 int slot, int frow, int fk, int nk) {
    const unsigned short* arow = src + frow * AST + fk * 8;
    const unsigned short* wrow = W + (size_t)slot * H_ + fk * 8;
    floatx4 acc0 = {0.f, 0.f, 0.f, 0.f}, acc1 = {0.f, 0.f, 0.f, 0.f};
    int k = 0;
    for (; k + 1 < nk; k += 2) {
        short8 a0 = *(const short8*)(arow + k * 32);
        short8 b0 = *(const short8*)(wrow + k * 32);
        short8 a1 = *(const short8*)(arow + k * 32 + 32);
        short8 b1 = *(const short8*)(wrow + k * 32 + 32);
        acc0 = __builtin_amdgcn_mfma_f32_16x16x32_bf16(a0, b0, acc0, 0, 0, 0);
        acc1 = __builtin_amdgcn_mfma_f32_16x16x32_bf16(a1, b1, acc1, 0, 0, 0);
    }
    if (k < nk) {
        short8 a0 = *(const short8*)(arow + k * 32);
        short8 b0 = *(const short8*)(wrow + k * 32);
        acc0 = __builtin_amdgcn_mfma_f32_16x16x32_bf16(a0, b0, acc0, 0, 0, 0);
    }
    floatx4 acc = acc0 + acc1;
    float bb = bias[slot];
    #pragma unroll
    for (int r = 0; r < 4; r++)                     // C/D: col=frow(slot), row m=fk*4+r
        dst[(fk * 4 + r) * AST + slot] = f2bf(fmaxf(acc[r] + bb, 0.f));
}

// ---- mega-kernel: 256 wgs x 16 rows; full 32-step sampling chain, activations in LDS ----
__global__ __launch_bounds__(256) void mega_kernel(
        const float* __restrict__ z,
        const unsigned short* __restrict__ W0bp,
        const float* __restrict__ b0p,
        const unsigned short* __restrict__ Wbp,
        const float* __restrict__ bhp,
        const float* __restrict__ Woutp,
        const float* __restrict__ bout,
        float* __restrict__ xout) {
    __shared__ unsigned short aS[3 * 16 * AST];     // a1,a2,a3: 16 rows x 1024 (+pad)
    __shared__ unsigned short xbS[16 * 32];         // running x, bf16
    __shared__ float xsS[16 * 32];                  // running x, fp32 (final output)
    __shared__ float zsS[16 * 32];
    __shared__ float red[16 * 16 * 2];

    const int tid = threadIdx.x;
    const int wave = tid >> 6, lane = tid & 63;
    const int frow = lane & 15, fk = lane >> 4;
    const int m0 = blockIdx.x * 16;

    {   // zero-init LDS state (uninitialized LDS could be NaN-pattern; zeros make
        // masked-weight products exactly 0 and match the reference x0=0)
        uint4 zz = {0u, 0u, 0u, 0u};
        uint4* p = (uint4*)aS;
        for (int i = tid; i < 3 * 16 * AST / 8; i += 256) p[i] = zz;
        if (tid < 64) ((uint4*)xbS)[tid] = zz;
        if (tid < 128) ((uint4*)xsS)[tid] = zz;
        if (tid < 128) ((float4*)zsS)[tid] = ((const float4*)(z + (size_t)m0 * 32))[tid];
    }
    __syncthreads();

    for (int idx = 0; idx < 32; idx++) {
        if (idx > 0) {
            // fresh band (degree idx-1), padded to 64 slots; pads are recomputed later
            int nb0 = (idx == 1) ? 0 : 33 * (idx - 1) + 1;
            if (nb0 > H_ - 64) nb0 = H_ - 64;
            const int slot = nb0 + wave * 16 + frow;
            const int nk = (33 * idx + 32) >> 5;    // ceil((33*idx+1)/32) K-chunks

            // layer 1 band: K=32 from xbS
            {
                short8 a = *(const short8*)(xbS + frow * 32 + fk * 8);
                short8 b = *(const short8*)(W0bp + (size_t)slot * 32 + fk * 8);
                floatx4 acc = {0.f, 0.f, 0.f, 0.f};
                acc = __builtin_amdgcn_mfma_f32_16x16x32_bf16(a, b, acc, 0, 0, 0);
                float bb = b0p[slot];
                #pragma unroll
                for (int r = 0; r < 4; r++)
                    aS[(fk * 4 + r) * AST + slot] = f2bf(fmaxf(acc[r] + bb, 0.f));
            }
            __syncthreads();
            // layer 2 band
            band_tile(aS, Wbp, bhp, aS + 16 * AST, slot, frow, fk, nk);
            __syncthreads();
            // layer 3 band
            band_tile(aS + 16 * AST, Wbp + (size_t)H_ * H_, bhp + H_,
                      aS + 2 * 16 * AST, slot, frow, fk, nk);
            __syncthreads();
        }

        // output step: theta cols idx / idx+32 (Woutp rows are zero beyond live prefix)
        {
            const int r = tid >> 4, s = tid & 15;
            const unsigned short* ar = aS + 2 * 16 * AST + r * AST + s * 64;
            const float* wmu = Woutp + (size_t)idx * H_ + s * 64;
            const float* wls = Woutp + (size_t)(idx + D_) * H_ + s * 64;
            float pm = 0.f, pl = 0.f;
            #pragma unroll
            for (int j8 = 0; j8 < 8; j8++) {
                union { uint4 v; unsigned short q[8]; } u;
                u.v = *(const uint4*)(ar + j8 * 8);
                #pragma unroll
                for (int e = 0; e < 8; e++) {
                    float av = bf2f(u.q[e]);
                    pm = fmaf(av, wmu[j8 * 8 + e], pm);
                    pl = fmaf(av, wls[j8 * 8 + e], pl);
                }
            }
            red[(r * 16 + s) * 2 + 0] = pm;
            red[(r * 16 + s) * 2 + 1] = pl;
        }
        __syncthreads();
        if (tid < 16) {
            float sm = bout[idx], sl = bout[idx + D_];
            #pragma unroll
            for (int s = 0; s < 16; s++) {
                sm += red[(tid * 16 + s) * 2 + 0];
                sl += red[(tid * 16 + s) * 2 + 1];
            }
            float xi = fmaf(zsS[tid * 32 + idx], expf(sl), sm);
            xsS[tid * 32 + idx] = xi;
            xbS[tid * 32 + idx] = f2bf(xi);
        }
        __syncthreads();
    }

    if (tid < 128)
        ((float4*)(xout + (size_t)m0 * 32))[tid] = ((const float4*)xsS)[tid];
}

extern "C" void kernel_launch(void* const* d_in, const int* in_sizes, int n_in,
                              void* d_out, int out_size, void* d_ws, size_t ws_size,
                              hipStream_t stream) {
    const float* z    = (const float*)d_in[0];
    const float* W0   = (const float*)d_in[1];
    const float* b0   = (const float*)d_in[2];
    const float* Wh   = (const float*)d_in[3];   // [2, H, H]
    const float* bh   = (const float*)d_in[4];   // [2, H]
    const float* Wout = (const float*)d_in[5];   // [64, H]
    const float* bout = (const float*)d_in[6];   // [64]

    float* x = (float*)d_out;                          // [B, D] output
    unsigned short* Wbp  = (unsigned short*)d_ws;      // [2, H, H] permuted+masked bf16
    unsigned short* W0bp = Wbp + 2 * H_ * H_;          // [H, 32]
    float* b0p   = (float*)(W0bp + H_ * D_);           // [H]
    float* bhp   = b0p + H_;                           // [2, H]
    float* Woutp = bhp + 2 * H_;                       // [64, H] permuted, tail-zeroed

    convert_whp<<<2 * H_, 256, 0, stream>>>(Wh, Wbp);
    convert_w0p<<<H_ * D_ / 256, 256, 0, stream>>>(W0, W0bp);
    convert_woutp<<<64 * H_ / 256, 256, 0, stream>>>(Wout, Woutp);
    convert_bias<<<3 * H_ / 256, 256, 0, stream>>>(b0, bh, b0p, bhp);

    mega_kernel<<<B_ / 16, 256, 0, stream>>>(z, W0bp, b0p, Wbp, bhp, Woutp, bout, x);
}

// Round 7
// 254.223 us; speedup vs baseline: 38.6028x; 1.6904x over previous
//
#include <hip/hip_runtime.h>
#include <hip/hip_bf16.h>

#define B_ 4096
#define D_ 32
#define H_ 1024
#define CS 512                 // activation chunk stride in shorts: [chunk][16 rows][32]
#define WPK_L 1079296          // shorts per hidden-layer weight pack (= 2048*sum(idx+1))

typedef __attribute__((ext_vector_type(8))) short short8;
typedef __attribute__((ext_vector_type(4))) float floatx4;

__device__ inline unsigned short f2bf(float f) {      // fp32 -> bf16 bits, RNE
    unsigned u = __float_as_uint(f);
    unsigned r = (u + 0x7FFF + ((u >> 16) & 1)) >> 16;
    return (unsigned short)r;
}

// degree-sorted order: degree 0 -> slots [0,34), degree d>=1 -> slots [33d+1, 33d+34)
__device__ inline int degs(int hp) { return (hp < 34) ? 0 : (hp - 1) / 33; }
__device__ inline int permf(int hp) {                  // sorted slot -> original h
    int d = degs(hp);
    int r = d ? (hp - 33 * d - 1) : hp;
    return d + 31 * r;
}
__device__ inline int band0(int idx) {                 // fresh-band base slot at step idx
    int nb0 = (idx == 1) ? 0 : 33 * idx - 32;
    return (nb0 > H_ - 64) ? H_ - 64 : nb0;
}

// ---- prep: hidden weights -> per-step band packs, B-frag order [chunk][slot64][32] ----
__global__ void pack_wh(const float* __restrict__ Wh, unsigned short* __restrict__ Wpk) {
    int b = blockIdx.x;                 // 2 layers * 31 idx * 32 max-chunks
    int l = b / 992;
    int r = b - l * 992;
    int idx = (r >> 5) + 1;
    int c = r & 31;
    if (c >= idx + 1) return;           // nk(idx) = idx+1 chunks
    int nb0 = band0(idx);
    size_t off = (size_t)l * WPK_L + (size_t)1024 * (idx - 1) * (idx + 2) + c * 2048;
    int t = threadIdx.x;
    int j = t >> 2, ko = (t & 3) * 8;
    int n = nb0 + j;
    int dn = degs(n);
    const float* srow = Wh + ((size_t)l << 20) + ((size_t)permf(n) << 10);
    union { unsigned short o[8]; uint4 v; } u;
    #pragma unroll
    for (int e = 0; e < 8; e++) {
        int k = c * 32 + ko + e;
        u.o[e] = (dn >= degs(k)) ? f2bf(srow[permf(k)]) : (unsigned short)0;
    }
    *(uint4*)(Wpk + off + j * 32 + ko) = u.v;
}

// ---- prep: W0 -> per-step band packs [idx][slot64][32] ----
__global__ void pack_w0(const float* __restrict__ W0, unsigned short* __restrict__ W0pk) {
    int idx = blockIdx.x + 1;
    int nb0 = band0(idx);
    int t = threadIdx.x;
    int j = t >> 2, ko = (t & 3) * 8;
    int n = nb0 + j;
    int dn = degs(n);
    const float* srow = W0 + (size_t)permf(n) * 32;
    union { unsigned short o[8]; uint4 v; } u;
    #pragma unroll
    for (int e = 0; e < 8; e++) {
        int k = ko + e;
        u.o[e] = (dn >= k) ? f2bf(srow[k]) : (unsigned short)0;
    }
    *(uint4*)(W0pk + (idx - 1) * 2048 + j * 32 + ko) = u.v;
}

// ---- prep: Wout -> bf16 B-frag packs [idx][chunk32][col16][32]; cols 0=mu,1=log_std ----
__global__ void pack_wout(const float* __restrict__ Wout, unsigned short* __restrict__ Wopk) {
    int b = blockIdx.x;                 // idx*32 + c
    int idx = b >> 5, c = b & 31;
    int ns = idx ? 33 * idx + 1 : 0;    // live prefix at step idx
    int t = threadIdx.x;
    #pragma unroll
    for (int uu = 0; uu < 2; uu++) {
        int e = t + uu * 256;
        int col = e >> 5, k = e & 31;
        int h = c * 32 + k;
        unsigned short v = 0;
        if (col < 2 && h < ns)
            v = f2bf(Wout[(size_t)(idx + col * 32) * H_ + permf(h)]);
        Wopk[(size_t)b * 512 + e] = v;
    }
}

// ---- prep: permuted biases ----
__global__ void convert_bias(const float* __restrict__ b0, const float* __restrict__ bh,
                             float* __restrict__ b0p, float* __restrict__ bhp) {
    int t = blockIdx.x * 256 + threadIdx.x;        // over 3*1024
    int hp = t & 1023;
    int p = permf(hp);
    if (t < 1024) b0p[hp] = b0[p];
    else if (t < 2048) bhp[hp] = bh[p];
    else bhp[1024 + hp] = bh[1024 + p];
}

// ---- band K-partial: one wave, 16 slots x 16 rows, chunks [c0,c1) ----
__device__ inline floatx4 band_partial(const unsigned short* act,
                                       const unsigned short* wpk,
                                       int frow, int fk, int s, int c0, int c1) {
    const unsigned short* ap = act + frow * 32 + fk * 8;
    const unsigned short* wp = wpk + s * 512 + frow * 32 + fk * 8;
    floatx4 x = {0.f, 0.f, 0.f, 0.f}, y = {0.f, 0.f, 0.f, 0.f};
    int c = c0;
    for (; c + 1 < c1; c += 2) {
        short8 a0 = *(const short8*)(ap + c * CS);
        short8 b0 = *(const short8*)(wp + (size_t)c * 2048);
        short8 a1 = *(const short8*)(ap + (c + 1) * CS);
        short8 b1 = *(const short8*)(wp + (size_t)(c + 1) * 2048);
        x = __builtin_amdgcn_mfma_f32_16x16x32_bf16(a0, b0, x, 0, 0, 0);
        y = __builtin_amdgcn_mfma_f32_16x16x32_bf16(a1, b1, y, 0, 0, 0);
    }
    if (c < c1) {
        short8 a0 = *(const short8*)(ap + c * CS);
        short8 b0 = *(const short8*)(wp + (size_t)c * 2048);
        x = __builtin_amdgcn_mfma_f32_16x16x32_bf16(a0, b0, x, 0, 0, 0);
    }
    return x + y;
}

// ---- mega-kernel: 256 wgs x 16 rows x 16 waves; full 32-step chain in LDS ----
__global__ __launch_bounds__(1024) void mega_kernel(
        const float* __restrict__ z,
        const unsigned short* __restrict__ W0pk,
        const float* __restrict__ b0p,
        const unsigned short* __restrict__ Wpk,
        const float* __restrict__ bhp,
        const unsigned short* __restrict__ Wopk,
        const float* __restrict__ bout,
        float* __restrict__ xout) {
    __shared__ unsigned short aS[3 * 32 * CS];     // a1,a2,a3 chunked [c][m][i], 32KB each
    __shared__ unsigned short xbS[16 * 32];        // running x, bf16 [m][32]
    __shared__ float xsS[16 * 32];                 // running x, fp32
    __shared__ float zsS[16 * 32];
    __shared__ floatx4 redS[12 * 64];              // K-split partials [q-1][s][lane]
    __shared__ float redO[16 * 32];                // out-dot partials [wave][col*16+m]

    const int tid = threadIdx.x;
    const int wave = tid >> 6, lane = tid & 63;
    const int frow = lane & 15, fk = lane >> 4;
    const int s = wave & 3, q = wave >> 2;
    const int m0 = blockIdx.x * 16;

    {   // zero-init LDS state (garbage x 0-weight must stay 0; matches x0 = 0)
        uint4 zz = {0u, 0u, 0u, 0u};
        for (int i = tid; i < 3 * 32 * CS / 8; i += 1024) ((uint4*)aS)[i] = zz;
        if (tid < 64)  ((uint4*)xbS)[tid] = zz;
        if (tid < 128) ((uint4*)xsS)[tid] = zz;
        if (tid < 128) ((float4*)zsS)[tid] = ((const float4*)(z + (size_t)m0 * 32))[tid];
    }
    __syncthreads();

    unsigned short* a1 = aS;
    unsigned short* a2 = aS + 32 * CS;
    unsigned short* a3 = aS + 64 * CS;

    for (int idx = 0; idx < 32; idx++) {
        if (idx > 0) {
            const int nb0 = band0(idx);
            const int slot = nb0 + s * 16 + frow;
            const int nk = idx + 1;
            const int nk4 = (nk + 3) >> 2;
            const int c0 = q * nk4;
            const int c1 = (c0 + nk4 < nk) ? c0 + nk4 : nk;
            const unsigned short* wb2 = Wpk + (size_t)1024 * (idx - 1) * (idx + 2);
            const unsigned short* wb3 = wb2 + WPK_L;
            const int wsl = (slot >> 5) * CS + (slot & 31);   // + m*32 for band writes

            // layer 1 band (waves q==0): K=32 single chunk
            if (q == 0) {
                short8 a = *(const short8*)(xbS + frow * 32 + fk * 8);
                short8 b = *(const short8*)(W0pk + (idx - 1) * 2048 + (s * 16 + frow) * 32 + fk * 8);
                floatx4 acc = {0.f, 0.f, 0.f, 0.f};
                acc = __builtin_amdgcn_mfma_f32_16x16x32_bf16(a, b, acc, 0, 0, 0);
                float bb = b0p[slot];
                #pragma unroll
                for (int r = 0; r < 4; r++)
                    a1[wsl + (fk * 4 + r) * 32] = f2bf(fmaxf(acc[r] + bb, 0.f));
            }
            __syncthreads();

            // layer 2 band: K-split partials + reduce
            {
                floatx4 p = band_partial(a1, wb2, frow, fk, s, c0, c1);
                if (q) redS[((q - 1) * 4 + s) * 64 + lane] = p;
                __syncthreads();
                if (q == 0) {
                    floatx4 t1 = redS[s * 64 + lane];
                    floatx4 t2 = redS[(4 + s) * 64 + lane];
                    floatx4 t3 = redS[(8 + s) * 64 + lane];
                    p = p + t1 + t2 + t3;
                    float bb = bhp[slot];
                    #pragma unroll
                    for (int r = 0; r < 4; r++)
                        a2[wsl + (fk * 4 + r) * 32] = f2bf(fmaxf(p[r] + bb, 0.f));
                }
                __syncthreads();
            }

            // layer 3 band
            {
                floatx4 p = band_partial(a2, wb3, frow, fk, s, c0, c1);
                if (q) redS[((q - 1) * 4 + s) * 64 + lane] = p;
                __syncthreads();
                if (q == 0) {
                    floatx4 t1 = redS[s * 64 + lane];
                    floatx4 t2 = redS[(4 + s) * 64 + lane];
                    floatx4 t3 = redS[(8 + s) * 64 + lane];
                    p = p + t1 + t2 + t3;
                    float bb = bhp[H_ + slot];
                    #pragma unroll
                    for (int r = 0; r < 4; r++)
                        a3[wsl + (fk * 4 + r) * 32] = f2bf(fmaxf(p[r] + bb, 0.f));
                }
                __syncthreads();
            }
        }

        // out-dot via MFMA: wave w covers a3 chunks {2w, 2w+1}; cols 0=mu, 1=log_std
        {
            floatx4 acc = {0.f, 0.f, 0.f, 0.f};
            #pragma unroll
            for (int cc = 0; cc < 2; cc++) {
                int c = wave * 2 + cc;
                short8 a = *(const short8*)(a3 + c * CS + frow * 32 + fk * 8);
                short8 b = *(const short8*)(Wopk + (size_t)((idx * 32 + c) * 16 + frow) * 32 + fk * 8);
                acc = __builtin_amdgcn_mfma_f32_16x16x32_bf16(a, b, acc, 0, 0, 0);
            }
            if (frow < 2) {
                #pragma unroll
                for (int r = 0; r < 4; r++)
                    redO[wave * 32 + frow * 16 + fk * 4 + r] = acc[r];
            }
        }
        __syncthreads();
        if (tid < 16) {
            float sm = bout[idx], sl = bout[idx + D_];
            #pragma unroll
            for (int w = 0; w < 16; w++) {
                sm += redO[w * 32 + tid];
                sl += redO[w * 32 + 16 + tid];
            }
            float xi = fmaf(zsS[tid * 32 + idx], expf(sl), sm);
            xsS[tid * 32 + idx] = xi;
            xbS[tid * 32 + idx] = f2bf(xi);
        }
        __syncthreads();
    }

    if (tid < 128)
        ((float4*)(xout + (size_t)m0 * 32))[tid] = ((const float4*)xsS)[tid];
}

extern "C" void kernel_launch(void* const* d_in, const int* in_sizes, int n_in,
                              void* d_out, int out_size, void* d_ws, size_t ws_size,
                              hipStream_t stream) {
    const float* z    = (const float*)d_in[0];
    const float* W0   = (const float*)d_in[1];
    const float* b0   = (const float*)d_in[2];
    const float* Wh   = (const float*)d_in[3];   // [2, H, H]
    const float* bh   = (const float*)d_in[4];   // [2, H]
    const float* Wout = (const float*)d_in[5];   // [64, H]
    const float* bout = (const float*)d_in[6];   // [64]

    float* x = (float*)d_out;                          // [B, D] output
    unsigned short* Wpk  = (unsigned short*)d_ws;      // 2 * WPK_L
    unsigned short* W0pk = Wpk + 2 * WPK_L;            // 31 * 2048
    unsigned short* Wopk = W0pk + 31 * 2048;           // 32 * 32 * 512
    float* b0p = (float*)(Wopk + 32 * 32 * 512);       // [H]
    float* bhp = b0p + H_;                             // [2, H]

    pack_wh<<<2 * 31 * 32, 256, 0, stream>>>(Wh, Wpk);
    pack_w0<<<31, 256, 0, stream>>>(W0, W0pk);
    pack_wout<<<32 * 32, 256, 0, stream>>>(Wout, Wopk);
    convert_bias<<<3 * H_ / 256, 256, 0, stream>>>(b0, bh, b0p, bhp);

    mega_kernel<<<B_ / 16, 1024, 0, stream>>>(z, W0pk, b0p, Wpk, bhp, Wopk, bout, x);
}